// Round 2
// baseline (7596.538 us; speedup 1.0000x reference)
//
#include <hip/hip_runtime.h>
#include <hip/hip_bf16.h>

#define BATCH 64
#define SEQ   2048
#define ISZ   256
#define H     256
#define G4    1024            // 4*H
#define M_TOT (BATCH*SEQ)     // 131072

typedef _Float16 half8  __attribute__((ext_vector_type(8)));
typedef _Float16 half2v __attribute__((ext_vector_type(2)));
typedef float    f32x4  __attribute__((ext_vector_type(4)));

union U32H2 { unsigned int u; half2v h; };
static __device__ __forceinline__ half2v u2h(unsigned int u){ U32H2 x; x.u = u; return x.h; }
union F32I { float f; int i; };

#if __has_builtin(__builtin_amdgcn_fdot2)
#define FDOT2(w,hp,acc) __builtin_amdgcn_fdot2(u2h(w), u2h(hp), (acc), false)
#else
static __device__ __forceinline__ float fdot2_sw(unsigned int w, unsigned int hp, float acc){
  half2v wv = u2h(w), hv = u2h(hp);
  return acc + (float)wv[0]*(float)hv[0] + (float)wv[1]*(float)hv[1];
}
#define FDOT2(w,hp,acc) fdot2_sw((w),(hp),(acc))
#endif

// Pure-VALU cross-lane add over lane pairs (t, t^1): DPP quad_perm(1,0,3,2).
// No LDS port, no SGPR write hazard (the readlane mistake of round 1).
static __device__ __forceinline__ float dpp_xor1(float v){
#if __has_builtin(__builtin_amdgcn_update_dpp)
  F32I a; a.f = v;
  F32I r; r.i = __builtin_amdgcn_update_dpp(0, a.i, 0xB1 /*quad_perm(1,0,3,2)*/, 0xF, 0xF, true);
  return r.f;
#else
  return __shfl_xor(v, 1, 64);
#endif
}

// ---------------------------------------------------------------------------
// Prep: f16-convert W_ih, fuse biases, and pack W_hh into the scan's
// per-thread quad stream Wpk.  Quad index Q in [0,32), thread t in [0,1024),
// u32 slot c in [0,4):
//   row(t,Q)  = (t & ~1) | (Q >> 4)          (thread owns rows t&~1 and t|1)
//   pair(t,Q,c) = (t&1)*64 + (Q&15)*4 + c    (thread owns k-half t&1)
//   Wpk[Q*4096 + t*4 + c] = pack_f16(W_hh[row][2*pair], W_hh[row][2*pair+1])
// Q 0..15: row t&~1 (all 16 h-chunks of the half); Q 16..31: row t|1.
// Scan keeps Q 0..23 in VGPRs and streams Q 24..31 from L2 every step.
// ---------------------------------------------------------------------------
__global__ __launch_bounds__(256) void prep_kernel(
    const float* __restrict__ Wih, const float* __restrict__ Whh,
    const float* __restrict__ bih, const float* __restrict__ bhh,
    _Float16* __restrict__ Wihf, unsigned int* __restrict__ Wpk,
    float* __restrict__ bias) {
  const int idx = blockIdx.x * 256 + threadIdx.x;     // grid covers 262144 exactly
  Wihf[idx] = (_Float16)Wih[idx];
  if (idx < 131072) {
    const int cc = idx & 3, t = (idx >> 2) & 1023, q = idx >> 12;
    const int row = (t & ~1) | (q >> 4);
    const int pi  = (t & 1) * 64 + (q & 15) * 4 + cc;
    U32H2 p;
    p.h[0] = (_Float16)Whh[row*256 + 2*pi];
    p.h[1] = (_Float16)Whh[row*256 + 2*pi + 1];
    Wpk[idx] = p.u;
  }
  if (idx < 1024) bias[idx] = bih[idx] + bhh[idx];
}

// ---------------------------------------------------------------------------
// Phase 1: x_proj GEMM (unchanged). C[m][n] = sum_k A[m][k]*B[n][k] + bias[n].
// ---------------------------------------------------------------------------
#define BM 128
#define BN 128
#define BK 32
#define LDA 40

__global__ __launch_bounds__(256) void xproj_gemm(
    const float* __restrict__ X, const _Float16* __restrict__ Wihf,
    const float* __restrict__ bias, _Float16* __restrict__ XP) {
  __shared__ _Float16 As[BM*LDA];
  __shared__ _Float16 Bs[BN*LDA];
  const int tid  = threadIdx.x;
  const int m0   = blockIdx.x * BM;
  const int n0   = blockIdx.y * BN;
  const int lane = tid & 63;
  const int w    = tid >> 6;
  const int wm   = w & 1, wn = w >> 1;
  const int row  = tid >> 1, hlf = tid & 1;

  f32x4 acc[4][4];
  #pragma unroll
  for (int mi = 0; mi < 4; ++mi)
    #pragma unroll
    for (int ni = 0; ni < 4; ++ni)
      acc[mi][ni] = (f32x4){0.f, 0.f, 0.f, 0.f};

  for (int kt = 0; kt < ISZ/BK; ++kt) {
    const int k0 = kt * BK;
    __syncthreads();
    {
      const float4* pa = (const float4*)(X + (size_t)(m0+row)*ISZ + k0 + hlf*16);
      float4 f0 = pa[0], f1 = pa[1], f2 = pa[2], f3 = pa[3];
      half8 h0, h1;
      h0[0]=(_Float16)f0.x; h0[1]=(_Float16)f0.y; h0[2]=(_Float16)f0.z; h0[3]=(_Float16)f0.w;
      h0[4]=(_Float16)f1.x; h0[5]=(_Float16)f1.y; h0[6]=(_Float16)f1.z; h0[7]=(_Float16)f1.w;
      h1[0]=(_Float16)f2.x; h1[1]=(_Float16)f2.y; h1[2]=(_Float16)f2.z; h1[3]=(_Float16)f2.w;
      h1[4]=(_Float16)f3.x; h1[5]=(_Float16)f3.y; h1[6]=(_Float16)f3.z; h1[7]=(_Float16)f3.w;
      *(half8*)&As[row*LDA + hlf*16]     = h0;
      *(half8*)&As[row*LDA + hlf*16 + 8] = h1;
      const half8* pb = (const half8*)(Wihf + (size_t)(n0+row)*ISZ + k0 + hlf*16);
      half8 b0 = pb[0], b1 = pb[1];
      *(half8*)&Bs[row*LDA + hlf*16]     = b0;
      *(half8*)&Bs[row*LDA + hlf*16 + 8] = b1;
    }
    __syncthreads();
    const int kch = (lane >> 4) * 8;
    const int rm  = wm*64 + (lane & 15);
    const int rn  = wn*64 + (lane & 15);
    half8 af[4], bf[4];
    #pragma unroll
    for (int i = 0; i < 4; ++i) {
      af[i] = *(const half8*)&As[(rm + i*16)*LDA + kch];
      bf[i] = *(const half8*)&Bs[(rn + i*16)*LDA + kch];
    }
    #pragma unroll
    for (int mi = 0; mi < 4; ++mi)
      #pragma unroll
      for (int ni = 0; ni < 4; ++ni)
        acc[mi][ni] = __builtin_amdgcn_mfma_f32_16x16x32_f16(af[mi], bf[ni], acc[mi][ni], 0, 0, 0);
  }
  const int col = lane & 15, qr = (lane >> 4) * 4;
  #pragma unroll
  for (int ni = 0; ni < 4; ++ni) {
    const int n  = n0 + wn*64 + ni*16 + col;
    const float bs = bias[n];
    #pragma unroll
    for (int mi = 0; mi < 4; ++mi) {
      #pragma unroll
      for (int r = 0; r < 4; ++r) {
        const int m = m0 + wm*64 + mi*16 + qr + r;
        XP[(size_t)m*G4 + n] = (_Float16)(acc[mi][ni][r] + bs);
      }
    }
  }
}

// ---------------------------------------------------------------------------
// Phase 2: persistent per-batch-item scan. 64 WGs x 1024 threads.
// Thread t computes HALF-dots (k-half = t&1) for rows t&~1 and t|1; the two
// halves of each row meet via a DPP quad_perm swap+add (lanes t, t^1).
//   - h read: 16 multicast ds_read_b128 per thread (half of h), the two
//     half-base addresses padded 8 banks apart (u32 offset 72) -> single-pass.
//   - W: 24 quads (96 VGPR) register-resident, 8 quads streamed from global
//     (L2-hot 128KB shared region) every step with a 2-deep register pipeline.
//     This removes the old 112 unique ds_read_b128/CU/step (the LDS-port
//     dominator) and frees 112KB LDS.
//   - no wave-wide SGPR broadcasts (round-1 readlane regression lesson).
// Gates land in act[] exactly as before; c/h update unchanged. 2 barriers.
// ---------------------------------------------------------------------------
__global__ __launch_bounds__(1024) void lstm_scan(
    const _Float16* __restrict__ XP, const uint4* __restrict__ WQ,
    float* __restrict__ out) {
  __shared__ float act[G4];                       // 4096 B
  __shared__ __align__(16) unsigned int h2[136];  // h as f16 pairs, halves at 0 / 72
  const int t = threadIdx.x;
  const int b = blockIdx.x;

  uint4 wq0[16], wq1[8];
  #pragma unroll
  for (int q = 0; q < 16; ++q) wq0[q] = WQ[q*1024 + t];        // row t&~1, chunks 0..15
  #pragma unroll
  for (int j = 0; j < 8; ++j)  wq1[j] = WQ[(16+j)*1024 + t];   // row t|1,  chunks 0..7

  if (t < 136) h2[t] = 0u;
  float c = 0.f;
  const _Float16* xb = XP + (size_t)b*SEQ*G4 + t;
  float xcur = (float)xb[0];
  float* outb = out + (size_t)b*SEQ*H;
  const unsigned int* hb = h2 + (t & 1) * 72;     // this thread's h half
  __syncthreads();

  #pragma unroll 1
  for (int s = 0; s < SEQ; ++s) {
    const int sn = (s + 1 < SEQ) ? (s + 1) : s;
    const _Float16 xnext = xb[(size_t)sn * G4];   // prefetch, used next iter

    // stream row-(t|1) chunks 8..15 from global (L2-hot); 2-deep pipeline.
    uint4 sA = WQ[24*1024 + t];
    uint4 sB = WQ[25*1024 + t];

    float a0 = 0.f, a1 = 0.f, b0 = 0.f, b1 = 0.f;
    #pragma unroll
    for (int q = 0; q < 16; ++q) {
      uint4 hq = *(const uint4*)(hb + 4*q);       // multicast LDS read
      uint4 w0 = wq0[q];
      a0 = FDOT2(w0.x, hq.x, a0); a1 = FDOT2(w0.y, hq.y, a1);
      a0 = FDOT2(w0.z, hq.z, a0); a1 = FDOT2(w0.w, hq.w, a1);
      uint4 w1;
      if (q < 8) { w1 = wq1[q]; }
      else       { w1 = sA; sA = sB; if (q < 14) sB = WQ[(18+q)*1024 + t]; }
      b0 = FDOT2(w1.x, hq.x, b0); b1 = FDOT2(w1.y, hq.y, b1);
      b0 = FDOT2(w1.z, hq.z, b0); b1 = FDOT2(w1.w, hq.w, b1);
    }
    // combine k-halves across the lane pair (pure VALU)
    const float p0 = a0 + a1, p1 = b0 + b1;
    const float g0 = p0 + dpp_xor1(p0);           // full dot, row t&~1
    const float g1 = p1 + dpp_xor1(p1);           // full dot, row t|1
    const float gate = ((t & 1) ? g1 : g0) + xcur;

    // rows 0-255=i(sig), 256-511=f(sig), 512-767=g(tanh), 768-1023=o(sig)
    float a;
    if (t < 512 || t >= 768) a = 1.f / (1.f + __expf(-gate));
    else                     a = 2.f / (1.f + __expf(-2.f*gate)) - 1.f;
    act[t] = a;
    __syncthreads();
    if (t < H) {
      const float gi = act[t], gf = act[H+t], gg = act[2*H+t], go = act[3*H+t];
      c = gf*c + gi*gg;
      const float th = 2.f / (1.f + __expf(-2.f*c)) - 1.f;
      const float h = go*th;
      outb[(size_t)s*H + t] = h;
      // h element e -> u32 pair e>>1, second half shifted +8 u32 (bank pad)
      ((_Float16*)h2)[t + (t >= 128 ? 16 : 0)] = (_Float16)h;
      if (s == SEQ-1) {
        out[(size_t)BATCH*SEQ*H + (size_t)b*H + t] = h;                    // final h
        out[(size_t)BATCH*SEQ*H + (size_t)BATCH*H + (size_t)b*H + t] = c;  // final c
      }
    }
    xcur = (float)xnext;
    __syncthreads();
  }
}

// ---------------------------------------------------------------------------
// ws layout: [ XP f16 256MB | Wihf f16 512KB | Wpk u32 512KB | bias f32 4KB ]
// ---------------------------------------------------------------------------
extern "C" void kernel_launch(void* const* d_in, const int* in_sizes, int n_in,
                              void* d_out, int out_size, void* d_ws, size_t ws_size,
                              hipStream_t stream) {
  const float* x   = (const float*)d_in[0];
  const float* Wih = (const float*)d_in[1];
  const float* Whh = (const float*)d_in[2];
  const float* bih = (const float*)d_in[3];
  const float* bhh = (const float*)d_in[4];
  float* out = (float*)d_out;

  char* ws = (char*)d_ws;
  const size_t XP_BYTES = (size_t)M_TOT * G4 * sizeof(_Float16);   // 268435456
  _Float16*     XPp  = (_Float16*)ws;
  _Float16*     Wihf = (_Float16*)(ws + XP_BYTES);
  unsigned int* Wpk  = (unsigned int*)(ws + XP_BYTES + 524288);
  float*        bias = (float*)(ws + XP_BYTES + 1048576);

  prep_kernel<<<dim3(1024),            dim3(256),  0, stream>>>(Wih, Whh, bih, bhh, Wihf, Wpk, bias);
  xproj_gemm <<<dim3(M_TOT/BM, G4/BN), dim3(256),  0, stream>>>(x, Wihf, bias, XPp);
  lstm_scan  <<<dim3(BATCH),           dim3(1024), 0, stream>>>(XPp, (const uint4*)Wpk, out);
}

// Round 3
// 4258.292 us; speedup vs baseline: 1.7839x; 1.7839x over previous
//
#include <hip/hip_runtime.h>
#include <hip/hip_bf16.h>

#define BATCH 64
#define SEQ   2048
#define ISZ   256
#define H     256
#define G4    1024            // 4*H
#define M_TOT (BATCH*SEQ)     // 131072

typedef _Float16 half8  __attribute__((ext_vector_type(8)));
typedef _Float16 half2v __attribute__((ext_vector_type(2)));
typedef float    f32x4  __attribute__((ext_vector_type(4)));

union U32H2 { unsigned int u; half2v h; };
static __device__ __forceinline__ half2v u2h(unsigned int u){ U32H2 x; x.u = u; return x.h; }

#if __has_builtin(__builtin_amdgcn_fdot2)
#define FDOT2(w,hp,acc) __builtin_amdgcn_fdot2(u2h(w), u2h(hp), (acc), false)
#else
static __device__ __forceinline__ float fdot2_sw(unsigned int w, unsigned int hp, float acc){
  half2v wv = u2h(w), hv = u2h(hp);
  return acc + (float)wv[0]*(float)hv[0] + (float)wv[1]*(float)hv[1];
}
#define FDOT2(w,hp,acc) fdot2_sw((w),(hp),(acc))
#endif

// ---------------------------------------------------------------------------
// Prep: f16-convert W_ih, pack W_hh into k2-major f16 pairs, fuse biases.
// Wpk[k2*1024 + t] = (f16)W_hh[t][2k2] | (f16)W_hh[t][2k2+1] << 16
// ---------------------------------------------------------------------------
__global__ __launch_bounds__(256) void prep_kernel(
    const float* __restrict__ Wih, const float* __restrict__ Whh,
    const float* __restrict__ bih, const float* __restrict__ bhh,
    _Float16* __restrict__ Wihf, unsigned int* __restrict__ Wpk,
    float* __restrict__ bias) {
  const int idx = blockIdx.x * 256 + threadIdx.x;     // grid covers 262144 exactly
  Wihf[idx] = (_Float16)Wih[idx];
  if (idx < 131072) {
    const int t = idx & 1023, k2 = idx >> 10;
    U32H2 p;
    p.h[0] = (_Float16)Whh[t*256 + 2*k2];
    p.h[1] = (_Float16)Whh[t*256 + 2*k2 + 1];
    Wpk[idx] = p.u;
  }
  if (idx < 1024) bias[idx] = bih[idx] + bhh[idx];
}

// ---------------------------------------------------------------------------
// Phase 1: x_proj GEMM (unchanged, proven). C = X * Wih^T + bias, f16 MFMA.
// ---------------------------------------------------------------------------
#define BM 128
#define BN 128
#define BK 32
#define LDA 40

__global__ __launch_bounds__(256) void xproj_gemm(
    const float* __restrict__ X, const _Float16* __restrict__ Wihf,
    const float* __restrict__ bias, _Float16* __restrict__ XP) {
  __shared__ _Float16 As[BM*LDA];
  __shared__ _Float16 Bs[BN*LDA];
  const int tid  = threadIdx.x;
  const int m0   = blockIdx.x * BM;
  const int n0   = blockIdx.y * BN;
  const int lane = tid & 63;
  const int w    = tid >> 6;
  const int wm   = w & 1, wn = w >> 1;
  const int row  = tid >> 1, hlf = tid & 1;   // staging map: 2 threads/row

  f32x4 acc[4][4];
  #pragma unroll
  for (int mi = 0; mi < 4; ++mi)
    #pragma unroll
    for (int ni = 0; ni < 4; ++ni)
      acc[mi][ni] = (f32x4){0.f, 0.f, 0.f, 0.f};

  for (int kt = 0; kt < ISZ/BK; ++kt) {
    const int k0 = kt * BK;
    __syncthreads();
    // stage A (fp32 -> f16) : 16 floats per thread
    {
      const float4* pa = (const float4*)(X + (size_t)(m0+row)*ISZ + k0 + hlf*16);
      float4 f0 = pa[0], f1 = pa[1], f2 = pa[2], f3 = pa[3];
      half8 h0, h1;
      h0[0]=(_Float16)f0.x; h0[1]=(_Float16)f0.y; h0[2]=(_Float16)f0.z; h0[3]=(_Float16)f0.w;
      h0[4]=(_Float16)f1.x; h0[5]=(_Float16)f1.y; h0[6]=(_Float16)f1.z; h0[7]=(_Float16)f1.w;
      h1[0]=(_Float16)f2.x; h1[1]=(_Float16)f2.y; h1[2]=(_Float16)f2.z; h1[3]=(_Float16)f2.w;
      h1[4]=(_Float16)f3.x; h1[5]=(_Float16)f3.y; h1[6]=(_Float16)f3.z; h1[7]=(_Float16)f3.w;
      *(half8*)&As[row*LDA + hlf*16]     = h0;
      *(half8*)&As[row*LDA + hlf*16 + 8] = h1;
      // stage B (already f16): 16 halves per thread
      const half8* pb = (const half8*)(Wihf + (size_t)(n0+row)*ISZ + k0 + hlf*16);
      half8 b0 = pb[0], b1 = pb[1];
      *(half8*)&Bs[row*LDA + hlf*16]     = b0;
      *(half8*)&Bs[row*LDA + hlf*16 + 8] = b1;
    }
    __syncthreads();
    const int kch = (lane >> 4) * 8;
    const int rm  = wm*64 + (lane & 15);
    const int rn  = wn*64 + (lane & 15);
    half8 af[4], bf[4];
    #pragma unroll
    for (int i = 0; i < 4; ++i) {
      af[i] = *(const half8*)&As[(rm + i*16)*LDA + kch];
      bf[i] = *(const half8*)&Bs[(rn + i*16)*LDA + kch];
    }
    #pragma unroll
    for (int mi = 0; mi < 4; ++mi)
      #pragma unroll
      for (int ni = 0; ni < 4; ++ni)
        acc[mi][ni] = __builtin_amdgcn_mfma_f32_16x16x32_f16(af[mi], bf[ni], acc[mi][ni], 0, 0, 0);
  }
  // epilogue: C/D layout col=lane&15, row=(lane>>4)*4+r
  const int col = lane & 15, qr = (lane >> 4) * 4;
  #pragma unroll
  for (int ni = 0; ni < 4; ++ni) {
    const int n  = n0 + wn*64 + ni*16 + col;
    const float bs = bias[n];
    #pragma unroll
    for (int mi = 0; mi < 4; ++mi) {
      #pragma unroll
      for (int r = 0; r < 4; ++r) {
        const int m = m0 + wm*64 + mi*16 + qr + r;
        XP[(size_t)m*G4 + n] = (_Float16)(acc[mi][ni][r] + bs);
      }
    }
  }
}

// ---------------------------------------------------------------------------
// Phase 2: persistent per-batch-item scan. 64 WGs x 1024 threads, thread t
// owns gate row t. Round-0 structure, with the critical fix:
//
//   __launch_bounds__(1024, 4)  -> VGPR cap 128 (4 waves/EU x 128 = 512-reg
//   file). Without the min-waves arg the compiler capped at 64 VGPRs and
//   SPILLED the whole weight array to scratch -- rounds 0-2 were secretly
//   scratch-reload bound (~400KB/CU/step through L1/L2), which is why
//   VGPR_Count read 64 everywhere and why LDS/VALU micro-opts regressed.
//
// W_hh residency: 96 f16-pairs truly in VGPRs (k2=0..95) + 32 pairs in LDS
// (8 quad-chunks, 131KB, [quad][tid] uint4 layout = conflict-free).
// h kept as packed f16 pairs in LDS (broadcast b128 reads). Gates exchanged
// through act[]; threads 0..255 own (c,h). 2 barriers/step.
// ---------------------------------------------------------------------------
#define NR  96    // register-resident pairs (k2 = 0..95)
#define NLQ 8     // LDS-resident pair-quads (k2 = 96..127)

__global__ __launch_bounds__(1024, 4) void lstm_scan(
    const _Float16* __restrict__ XP, const unsigned int* __restrict__ Wpk,
    float* __restrict__ out) {
  __shared__ uint4 wlds[NLQ*1024];        // 131072 B
  __shared__ float act[G4];               // 4096 B
  __shared__ unsigned int h2[H/2];        // 512 B: h as packed f16 pairs
  const int t = threadIdx.x;
  const int b = blockIdx.x;

  unsigned int wreg[NR];
  #pragma unroll
  for (int i = 0; i < NR; ++i) wreg[i] = Wpk[i*1024 + t];
  #pragma unroll
  for (int q = 0; q < NLQ; ++q) {
    uint4 v;
    v.x = Wpk[(NR + 4*q + 0)*1024 + t];
    v.y = Wpk[(NR + 4*q + 1)*1024 + t];
    v.z = Wpk[(NR + 4*q + 2)*1024 + t];
    v.w = Wpk[(NR + 4*q + 3)*1024 + t];
    wlds[q*1024 + t] = v;
  }
  if (t < H/2) h2[t] = 0u;
  float c = 0.f;
  const _Float16* xb = XP + (size_t)b*SEQ*G4 + t;
  float xcur = (float)xb[0];
  float* outb = out + (size_t)b*SEQ*H;
  __syncthreads();

  #pragma unroll 1
  for (int s = 0; s < SEQ; ++s) {
    const int sn = (s + 1 < SEQ) ? (s + 1) : s;
    const _Float16 xnext = xb[(size_t)sn * G4];   // prefetch, used next iter

    float acc0 = xcur, acc1 = 0.f;
    #pragma unroll
    for (int q = 0; q < NR/4; ++q) {              // k2 = 0..95 (registers)
      uint4 hq = *(const uint4*)(h2 + 4*q);
      acc0 = FDOT2(wreg[4*q+0], hq.x, acc0);
      acc1 = FDOT2(wreg[4*q+1], hq.y, acc1);
      acc0 = FDOT2(wreg[4*q+2], hq.z, acc0);
      acc1 = FDOT2(wreg[4*q+3], hq.w, acc1);
    }
    #pragma unroll
    for (int q = 0; q < NLQ; ++q) {               // k2 = 96..127 (LDS)
      uint4 hq = *(const uint4*)(h2 + NR + 4*q);
      uint4 wv = wlds[q*1024 + t];
      acc0 = FDOT2(wv.x, hq.x, acc0);
      acc1 = FDOT2(wv.y, hq.y, acc1);
      acc0 = FDOT2(wv.z, hq.z, acc0);
      acc1 = FDOT2(wv.w, hq.w, acc1);
    }
    const float gate = acc0 + acc1;
    // rows 0-255=i(sig), 256-511=f(sig), 512-767=g(tanh), 768-1023=o(sig);
    // branch is wave-uniform.
    float a;
    if (t < 512 || t >= 768) a = 1.f / (1.f + __expf(-gate));
    else                     a = 2.f / (1.f + __expf(-2.f*gate)) - 1.f;
    act[t] = a;
    __syncthreads();
    if (t < H) {
      const float gi = act[t], gf = act[H+t], gg = act[2*H+t], go = act[3*H+t];
      c = gf*c + gi*gg;
      const float th = 2.f / (1.f + __expf(-2.f*c)) - 1.f;
      const float h = go*th;
      outb[(size_t)s*H + t] = h;
      ((_Float16*)h2)[t] = (_Float16)h;
      if (s == SEQ-1) {
        out[(size_t)BATCH*SEQ*H + (size_t)b*H + t] = h;                 // final h
        out[(size_t)BATCH*SEQ*H + (size_t)BATCH*H + (size_t)b*H + t] = c; // final c
      }
    }
    xcur = (float)xnext;
    __syncthreads();
  }
}

// ---------------------------------------------------------------------------
// ws layout: [ XP f16 256MB | Wihf f16 512KB | Wpk u32 512KB | bias f32 4KB ]
// ---------------------------------------------------------------------------
extern "C" void kernel_launch(void* const* d_in, const int* in_sizes, int n_in,
                              void* d_out, int out_size, void* d_ws, size_t ws_size,
                              hipStream_t stream) {
  const float* x   = (const float*)d_in[0];
  const float* Wih = (const float*)d_in[1];
  const float* Whh = (const float*)d_in[2];
  const float* bih = (const float*)d_in[3];
  const float* bhh = (const float*)d_in[4];
  float* out = (float*)d_out;

  char* ws = (char*)d_ws;
  const size_t XP_BYTES = (size_t)M_TOT * G4 * sizeof(_Float16);   // 268435456
  _Float16*     XPp  = (_Float16*)ws;
  _Float16*     Wihf = (_Float16*)(ws + XP_BYTES);
  unsigned int* Wpk  = (unsigned int*)(ws + XP_BYTES + 524288);
  float*        bias = (float*)(ws + XP_BYTES + 1048576);

  prep_kernel<<<dim3(1024),            dim3(256),  0, stream>>>(Wih, Whh, bih, bhh, Wihf, Wpk, bias);
  xproj_gemm <<<dim3(M_TOT/BM, G4/BN), dim3(256),  0, stream>>>(x, Wihf, bias, XPp);
  lstm_scan  <<<dim3(BATCH),           dim3(1024), 0, stream>>>(XPp, Wpk, out);
}

// Round 5
// 4246.721 us; speedup vs baseline: 1.7888x; 1.0027x over previous
//
#include <hip/hip_runtime.h>
#include <hip/hip_bf16.h>

#define BATCH 64
#define SEQ   2048
#define ISZ   256
#define H     256
#define G4    1024            // 4*H
#define M_TOT (BATCH*SEQ)     // 131072

typedef _Float16 half8  __attribute__((ext_vector_type(8)));
typedef _Float16 half2v __attribute__((ext_vector_type(2)));
typedef float    f32x4  __attribute__((ext_vector_type(4)));

union U32H2 { unsigned int u; half2v h; };
static __device__ __forceinline__ half2v u2h(unsigned int u){ U32H2 x; x.u = u; return x.h; }

#if __has_builtin(__builtin_amdgcn_fdot2)
#define FDOT2(w,hp,acc) __builtin_amdgcn_fdot2(u2h(w), u2h(hp), (acc), false)
#else
static __device__ __forceinline__ float fdot2_sw(unsigned int w, unsigned int hp, float acc){
  half2v wv = u2h(w), hv = u2h(hp);
  return acc + (float)wv[0]*(float)hv[0] + (float)wv[1]*(float)hv[1];
}
#define FDOT2(w,hp,acc) fdot2_sw((w),(hp),(acc))
#endif

// ---------------------------------------------------------------------------
// Prep: f16-convert W_ih, pack W_hh into k2-major f16 pairs, fuse biases.
// Wpk[k2*1024 + t] = (f16)W_hh[t][2k2] | (f16)W_hh[t][2k2+1] << 16
// ---------------------------------------------------------------------------
__global__ __launch_bounds__(256) void prep_kernel(
    const float* __restrict__ Wih, const float* __restrict__ Whh,
    const float* __restrict__ bih, const float* __restrict__ bhh,
    _Float16* __restrict__ Wihf, unsigned int* __restrict__ Wpk,
    float* __restrict__ bias) {
  const int idx = blockIdx.x * 256 + threadIdx.x;     // grid covers 262144 exactly
  Wihf[idx] = (_Float16)Wih[idx];
  if (idx < 131072) {
    const int t = idx & 1023, k2 = idx >> 10;
    U32H2 p;
    p.h[0] = (_Float16)Whh[t*256 + 2*k2];
    p.h[1] = (_Float16)Whh[t*256 + 2*k2 + 1];
    Wpk[idx] = p.u;
  }
  if (idx < 1024) bias[idx] = bih[idx] + bhh[idx];
}

// ---------------------------------------------------------------------------
// Phase 1: x_proj GEMM (unchanged, proven). C = X * Wih^T + bias, f16 MFMA.
// ---------------------------------------------------------------------------
#define BM 128
#define BN 128
#define BK 32
#define LDA 40

__global__ __launch_bounds__(256) void xproj_gemm(
    const float* __restrict__ X, const _Float16* __restrict__ Wihf,
    const float* __restrict__ bias, _Float16* __restrict__ XP) {
  __shared__ _Float16 As[BM*LDA];
  __shared__ _Float16 Bs[BN*LDA];
  const int tid  = threadIdx.x;
  const int m0   = blockIdx.x * BM;
  const int n0   = blockIdx.y * BN;
  const int lane = tid & 63;
  const int w    = tid >> 6;
  const int wm   = w & 1, wn = w >> 1;
  const int row  = tid >> 1, hlf = tid & 1;   // staging map: 2 threads/row

  f32x4 acc[4][4];
  #pragma unroll
  for (int mi = 0; mi < 4; ++mi)
    #pragma unroll
    for (int ni = 0; ni < 4; ++ni)
      acc[mi][ni] = (f32x4){0.f, 0.f, 0.f, 0.f};

  for (int kt = 0; kt < ISZ/BK; ++kt) {
    const int k0 = kt * BK;
    __syncthreads();
    // stage A (fp32 -> f16) : 16 floats per thread
    {
      const float4* pa = (const float4*)(X + (size_t)(m0+row)*ISZ + k0 + hlf*16);
      float4 f0 = pa[0], f1 = pa[1], f2 = pa[2], f3 = pa[3];
      half8 h0, h1;
      h0[0]=(_Float16)f0.x; h0[1]=(_Float16)f0.y; h0[2]=(_Float16)f0.z; h0[3]=(_Float16)f0.w;
      h0[4]=(_Float16)f1.x; h0[5]=(_Float16)f1.y; h0[6]=(_Float16)f1.z; h0[7]=(_Float16)f1.w;
      h1[0]=(_Float16)f2.x; h1[1]=(_Float16)f2.y; h1[2]=(_Float16)f2.z; h1[3]=(_Float16)f2.w;
      h1[4]=(_Float16)f3.x; h1[5]=(_Float16)f3.y; h1[6]=(_Float16)f3.z; h1[7]=(_Float16)f3.w;
      *(half8*)&As[row*LDA + hlf*16]     = h0;
      *(half8*)&As[row*LDA + hlf*16 + 8] = h1;
      // stage B (already f16): 16 halves per thread
      const half8* pb = (const half8*)(Wihf + (size_t)(n0+row)*ISZ + k0 + hlf*16);
      half8 b0 = pb[0], b1 = pb[1];
      *(half8*)&Bs[row*LDA + hlf*16]     = b0;
      *(half8*)&Bs[row*LDA + hlf*16 + 8] = b1;
    }
    __syncthreads();
    const int kch = (lane >> 4) * 8;
    const int rm  = wm*64 + (lane & 15);
    const int rn  = wn*64 + (lane & 15);
    half8 af[4], bf[4];
    #pragma unroll
    for (int i = 0; i < 4; ++i) {
      af[i] = *(const half8*)&As[(rm + i*16)*LDA + kch];
      bf[i] = *(const half8*)&Bs[(rn + i*16)*LDA + kch];
    }
    #pragma unroll
    for (int mi = 0; mi < 4; ++mi)
      #pragma unroll
      for (int ni = 0; ni < 4; ++ni)
        acc[mi][ni] = __builtin_amdgcn_mfma_f32_16x16x32_f16(af[mi], bf[ni], acc[mi][ni], 0, 0, 0);
  }
  // epilogue: C/D layout col=lane&15, row=(lane>>4)*4+r
  const int col = lane & 15, qr = (lane >> 4) * 4;
  #pragma unroll
  for (int ni = 0; ni < 4; ++ni) {
    const int n  = n0 + wn*64 + ni*16 + col;
    const float bs = bias[n];
    #pragma unroll
    for (int mi = 0; mi < 4; ++mi) {
      #pragma unroll
      for (int r = 0; r < 4; ++r) {
        const int m = m0 + wm*64 + mi*16 + qr + r;
        XP[(size_t)m*G4 + n] = (_Float16)(acc[mi][ni][r] + bs);
      }
    }
  }
}

// ---------------------------------------------------------------------------
// Phase 2: persistent per-batch-item scan. 64 WGs x 1024 threads, thread t
// owns gate row t.
//
// RESIDENCY FIX (rounds 0-3 diagnosis): VGPR_Count=64 every round + perf
// insensitive to NR means the compiler SANK the Wpk loads into the s-loop
// (restrict-const loads are re-executable) -> ~1536 VMEM wave-insts/CU/step
// -> VMEM-issue bound (~6000 cyc issue, 4600 measured). Fix:
//   (a) __launch_bounds__(1024, 4): register budget 128/thread (LDS=135KB
//       already limits to one block/CU, so 4 waves/EU costs nothing);
//   (b) asm volatile "+v" pin on every wreg element right after the load
//       loop: the asm reads+writes each value, so loads CANNOT be sunk past
//       it; values are live across the scan loop and must stay in VGPRs.
// Zero instructions emitted by the pins.
//
// W_hh residency: 96 f16-pairs in VGPRs (k2=0..95) + 32 pairs in LDS
// (8 quad-chunks, 131KB, [quad][tid] uint4 layout = conflict-free).
// h kept as packed f16 pairs in LDS (broadcast b128 reads). Gates exchanged
// through act[]; threads 0..255 own (c,h). 2 barriers/step.
// ---------------------------------------------------------------------------
#define NR  96    // register-resident pairs (k2 = 0..95)
#define NLQ 8     // LDS-resident pair-quads (k2 = 96..127)

__global__ __launch_bounds__(1024, 4) void lstm_scan(
    const _Float16* __restrict__ XP, const unsigned int* __restrict__ Wpk,
    float* __restrict__ out) {
  __shared__ uint4 wlds[NLQ*1024];        // 131072 B
  __shared__ float act[G4];               // 4096 B
  __shared__ unsigned int h2[H/2];        // 512 B: h as packed f16 pairs
  const int t = threadIdx.x;
  const int b = blockIdx.x;

  unsigned int wreg[NR];
  #pragma unroll
  for (int i = 0; i < NR; ++i) wreg[i] = Wpk[i*1024 + t];
  // Pin: forces each weight into a VGPR here; blocks load-sinking into the
  // scan loop (the mechanism that made rounds 0-3 VMEM-issue-bound).
  #pragma unroll
  for (int i = 0; i < NR; ++i) asm volatile("" : "+v"(wreg[i]));

  #pragma unroll
  for (int q = 0; q < NLQ; ++q) {
    uint4 v;
    v.x = Wpk[(NR + 4*q + 0)*1024 + t];
    v.y = Wpk[(NR + 4*q + 1)*1024 + t];
    v.z = Wpk[(NR + 4*q + 2)*1024 + t];
    v.w = Wpk[(NR + 4*q + 3)*1024 + t];
    wlds[q*1024 + t] = v;
  }
  if (t < H/2) h2[t] = 0u;
  float c = 0.f;
  const _Float16* xb = XP + (size_t)b*SEQ*G4 + t;
  float xcur = (float)xb[0];
  float* outb = out + (size_t)b*SEQ*H;
  __syncthreads();

  #pragma unroll 1
  for (int s = 0; s < SEQ; ++s) {
    const int sn = (s + 1 < SEQ) ? (s + 1) : s;
    const _Float16 xnext = xb[(size_t)sn * G4];   // prefetch, used next iter

    float acc0 = xcur, acc1 = 0.f;
    #pragma unroll
    for (int q = 0; q < NR/4; ++q) {              // k2 = 0..95 (registers)
      uint4 hq = *(const uint4*)(h2 + 4*q);
      acc0 = FDOT2(wreg[4*q+0], hq.x, acc0);
      acc1 = FDOT2(wreg[4*q+1], hq.y, acc1);
      acc0 = FDOT2(wreg[4*q+2], hq.z, acc0);
      acc1 = FDOT2(wreg[4*q+3], hq.w, acc1);
    }
    #pragma unroll
    for (int q = 0; q < NLQ; ++q) {               // k2 = 96..127 (LDS)
      uint4 hq = *(const uint4*)(h2 + NR + 4*q);
      uint4 wv = wlds[q*1024 + t];
      acc0 = FDOT2(wv.x, hq.x, acc0);
      acc1 = FDOT2(wv.y, hq.y, acc1);
      acc0 = FDOT2(wv.z, hq.z, acc0);
      acc1 = FDOT2(wv.w, hq.w, acc1);
    }
    const float gate = acc0 + acc1;
    // rows 0-255=i(sig), 256-511=f(sig), 512-767=g(tanh), 768-1023=o(sig);
    // branch is wave-uniform.
    float a;
    if (t < 512 || t >= 768) a = 1.f / (1.f + __expf(-gate));
    else                     a = 2.f / (1.f + __expf(-2.f*gate)) - 1.f;
    act[t] = a;
    __syncthreads();
    if (t < H) {
      const float gi = act[t], gf = act[H+t], gg = act[2*H+t], go = act[3*H+t];
      c = gf*c + gi*gg;
      const float th = 2.f / (1.f + __expf(-2.f*c)) - 1.f;
      const float h = go*th;
      outb[(size_t)s*H + t] = h;
      ((_Float16*)h2)[t] = (_Float16)h;
      if (s == SEQ-1) {
        out[(size_t)BATCH*SEQ*H + (size_t)b*H + t] = h;                 // final h
        out[(size_t)BATCH*SEQ*H + (size_t)BATCH*H + (size_t)b*H + t] = c; // final c
      }
    }
    xcur = (float)xnext;
    __syncthreads();
  }
}

// ---------------------------------------------------------------------------
// ws layout: [ XP f16 256MB | Wihf f16 512KB | Wpk u32 512KB | bias f32 4KB ]
// ---------------------------------------------------------------------------
extern "C" void kernel_launch(void* const* d_in, const int* in_sizes, int n_in,
                              void* d_out, int out_size, void* d_ws, size_t ws_size,
                              hipStream_t stream) {
  const float* x   = (const float*)d_in[0];
  const float* Wih = (const float*)d_in[1];
  const float* Whh = (const float*)d_in[2];
  const float* bih = (const float*)d_in[3];
  const float* bhh = (const float*)d_in[4];
  float* out = (float*)d_out;

  char* ws = (char*)d_ws;
  const size_t XP_BYTES = (size_t)M_TOT * G4 * sizeof(_Float16);   // 268435456
  _Float16*     XPp  = (_Float16*)ws;
  _Float16*     Wihf = (_Float16*)(ws + XP_BYTES);
  unsigned int* Wpk  = (unsigned int*)(ws + XP_BYTES + 524288);
  float*        bias = (float*)(ws + XP_BYTES + 1048576);

  prep_kernel<<<dim3(1024),            dim3(256),  0, stream>>>(Wih, Whh, bih, bhh, Wihf, Wpk, bias);
  xproj_gemm <<<dim3(M_TOT/BM, G4/BN), dim3(256),  0, stream>>>(x, Wihf, bias, XPp);
  lstm_scan  <<<dim3(BATCH),           dim3(1024), 0, stream>>>(XPp, Wpk, out);
}

// Round 6
// 3754.902 us; speedup vs baseline: 2.0231x; 1.1310x over previous
//
#include <hip/hip_runtime.h>
#include <hip/hip_bf16.h>

#define BATCH 64
#define SEQ   2048
#define ISZ   256
#define H     256
#define G4    1024            // 4*H
#define M_TOT (BATCH*SEQ)     // 131072

typedef _Float16 half8  __attribute__((ext_vector_type(8)));
typedef _Float16 half2v __attribute__((ext_vector_type(2)));
typedef float    f32x4  __attribute__((ext_vector_type(4)));

union U32H2 { unsigned int u; half2v h; };
static __device__ __forceinline__ half2v u2h(unsigned int u){ U32H2 x; x.u = u; return x.h; }
union F32I { float f; int i; };

#if __has_builtin(__builtin_amdgcn_fdot2)
#define FDOT2(w,hp,acc) __builtin_amdgcn_fdot2(u2h(w), u2h(hp), (acc), false)
#else
static __device__ __forceinline__ float fdot2_sw(unsigned int w, unsigned int hp, float acc){
  half2v wv = u2h(w), hv = u2h(hp);
  return acc + (float)wv[0]*(float)hv[0] + (float)wv[1]*(float)hv[1];
}
#define FDOT2(w,hp,acc) fdot2_sw((w),(hp),(acc))
#endif

// Pure-VALU cross-lane adds within a quad (lanes t^1, t^2). DPP quad_perm:
// full-rate, no LDS port, no SGPR-write hazard (round-1 readlane lesson).
static __device__ __forceinline__ float dpp_xor1(float v){
#if __has_builtin(__builtin_amdgcn_update_dpp)
  F32I a; a.f = v;
  F32I r; r.i = __builtin_amdgcn_update_dpp(0, a.i, 0xB1 /*quad_perm(1,0,3,2)*/, 0xF, 0xF, true);
  return r.f;
#else
  return __shfl_xor(v, 1, 64);
#endif
}
static __device__ __forceinline__ float dpp_xor2(float v){
#if __has_builtin(__builtin_amdgcn_update_dpp)
  F32I a; a.f = v;
  F32I r; r.i = __builtin_amdgcn_update_dpp(0, a.i, 0x4E /*quad_perm(2,3,0,1)*/, 0xF, 0xF, true);
  return r.f;
#else
  return __shfl_xor(v, 2, 64);
#endif
}

// ---------------------------------------------------------------------------
// Prep: f16-convert W_ih, fuse biases, and pack W_hh into the scan's
// k-quarter-split layout Wq. Thread t of the scan owns k-quarter (t&3) of
// rows 4*(t>>2)..+3.  For j in [0,128) with r=j>>5 (row offset), i=j&31
// (pair within quarter):
//   Wq[j*1024 + t] = pack_f16( W_hh[4*(t>>2)+r][2*((t&3)*32+i)], ...+1 )
// j 0..95 -> scan registers (rows +0,+1,+2); j 96..127 -> scan LDS (row +3).
// ---------------------------------------------------------------------------
__global__ __launch_bounds__(256) void prep_kernel(
    const float* __restrict__ Wih, const float* __restrict__ Whh,
    const float* __restrict__ bih, const float* __restrict__ bhh,
    _Float16* __restrict__ Wihf, unsigned int* __restrict__ Wq,
    float* __restrict__ bias) {
  const int idx = blockIdx.x * 256 + threadIdx.x;     // grid covers 262144 exactly
  Wihf[idx] = (_Float16)Wih[idx];
  if (idx < 131072) {
    const int t = idx & 1023, j = idx >> 10;
    const int r = j >> 5, i = j & 31;
    const int row = 4*(t >> 2) + r;
    const int k2  = (t & 3)*32 + i;
    U32H2 p;
    p.h[0] = (_Float16)Whh[row*256 + 2*k2];
    p.h[1] = (_Float16)Whh[row*256 + 2*k2 + 1];
    Wq[idx] = p.u;
  }
  if (idx < 1024) bias[idx] = bih[idx] + bhh[idx];
}

// ---------------------------------------------------------------------------
// Phase 1: x_proj GEMM (unchanged, proven). C = X * Wih^T + bias, f16 MFMA.
// ---------------------------------------------------------------------------
#define BM 128
#define BN 128
#define BK 32
#define LDA 40

__global__ __launch_bounds__(256) void xproj_gemm(
    const float* __restrict__ X, const _Float16* __restrict__ Wihf,
    const float* __restrict__ bias, _Float16* __restrict__ XP) {
  __shared__ _Float16 As[BM*LDA];
  __shared__ _Float16 Bs[BN*LDA];
  const int tid  = threadIdx.x;
  const int m0   = blockIdx.x * BM;
  const int n0   = blockIdx.y * BN;
  const int lane = tid & 63;
  const int w    = tid >> 6;
  const int wm   = w & 1, wn = w >> 1;
  const int row  = tid >> 1, hlf = tid & 1;   // staging map: 2 threads/row

  f32x4 acc[4][4];
  #pragma unroll
  for (int mi = 0; mi < 4; ++mi)
    #pragma unroll
    for (int ni = 0; ni < 4; ++ni)
      acc[mi][ni] = (f32x4){0.f, 0.f, 0.f, 0.f};

  for (int kt = 0; kt < ISZ/BK; ++kt) {
    const int k0 = kt * BK;
    __syncthreads();
    // stage A (fp32 -> f16) : 16 floats per thread
    {
      const float4* pa = (const float4*)(X + (size_t)(m0+row)*ISZ + k0 + hlf*16);
      float4 f0 = pa[0], f1 = pa[1], f2 = pa[2], f3 = pa[3];
      half8 h0, h1;
      h0[0]=(_Float16)f0.x; h0[1]=(_Float16)f0.y; h0[2]=(_Float16)f0.z; h0[3]=(_Float16)f0.w;
      h0[4]=(_Float16)f1.x; h0[5]=(_Float16)f1.y; h0[6]=(_Float16)f1.z; h0[7]=(_Float16)f1.w;
      h1[0]=(_Float16)f2.x; h1[1]=(_Float16)f2.y; h1[2]=(_Float16)f2.z; h1[3]=(_Float16)f2.w;
      h1[4]=(_Float16)f3.x; h1[5]=(_Float16)f3.y; h1[6]=(_Float16)f3.z; h1[7]=(_Float16)f3.w;
      *(half8*)&As[row*LDA + hlf*16]     = h0;
      *(half8*)&As[row*LDA + hlf*16 + 8] = h1;
      // stage B (already f16): 16 halves per thread
      const half8* pb = (const half8*)(Wihf + (size_t)(n0+row)*ISZ + k0 + hlf*16);
      half8 b0 = pb[0], b1 = pb[1];
      *(half8*)&Bs[row*LDA + hlf*16]     = b0;
      *(half8*)&Bs[row*LDA + hlf*16 + 8] = b1;
    }
    __syncthreads();
    const int kch = (lane >> 4) * 8;
    const int rm  = wm*64 + (lane & 15);
    const int rn  = wn*64 + (lane & 15);
    half8 af[4], bf[4];
    #pragma unroll
    for (int i = 0; i < 4; ++i) {
      af[i] = *(const half8*)&As[(rm + i*16)*LDA + kch];
      bf[i] = *(const half8*)&Bs[(rn + i*16)*LDA + kch];
    }
    #pragma unroll
    for (int mi = 0; mi < 4; ++mi)
      #pragma unroll
      for (int ni = 0; ni < 4; ++ni)
        acc[mi][ni] = __builtin_amdgcn_mfma_f32_16x16x32_f16(af[mi], bf[ni], acc[mi][ni], 0, 0, 0);
  }
  // epilogue: C/D layout col=lane&15, row=(lane>>4)*4+r
  const int col = lane & 15, qr = (lane >> 4) * 4;
  #pragma unroll
  for (int ni = 0; ni < 4; ++ni) {
    const int n  = n0 + wn*64 + ni*16 + col;
    const float bs = bias[n];
    #pragma unroll
    for (int mi = 0; mi < 4; ++mi) {
      #pragma unroll
      for (int r = 0; r < 4; ++r) {
        const int m = m0 + wm*64 + mi*16 + qr + r;
        XP[(size_t)m*G4 + n] = (_Float16)(acc[mi][ni][r] + bs);
      }
    }
  }
}

// ---------------------------------------------------------------------------
// Phase 2: persistent per-batch-item scan. 64 WGs x 1024 threads.
//
// k-QUARTER SPLIT (this round's single change). Rounds 0/3/5 are all bound
// by ~640 ds_read_b128 wave-insts/CU/step (512 h-broadcast + 128 wlds);
// each returns 1024B to the RF regardless of address uniformity -> LDS
// return-bandwidth bound (~4600 cyc/step measured). Residency knobs proved
// neutral (R3/R5: VGPR=64, perf identical).
//
// Thread t computes k-quarter (t&3) partial dots for rows 4*(t>>2)..+3,
// reading only 8 uint4 of h (quarter) -> h-traffic 512->128 wave-b128/CU.
// Quarter partials combine via 2-round quad DPP butterfly (pure VALU,
// lanes of a quad are same-wave); thread t then holds row t's full gate --
// activation/act[]/tail identical to round 0.
//
// h2 layout: 4 quarter regions padded 36 u32 apart (quarters hit disjoint
// bank groups -> 4-address multicast is conflict-free).
// W: rows +0,+1,+2 (96 u32) register/AGPR-resident; row +3 (8 uint4) in
// wlds -- same residency shape as round 0.  2 barriers/step.
// ---------------------------------------------------------------------------
__global__ __launch_bounds__(1024, 4) void lstm_scan(
    const _Float16* __restrict__ XP, const unsigned int* __restrict__ Wq,
    float* __restrict__ out) {
  __shared__ uint4 wlds[8*1024];                  // 131072 B (row +3 quads)
  __shared__ float act[G4];                       // 4096 B
  __shared__ __align__(16) unsigned int h2[144];  // 4 padded h-quarters (36 u32 each)
  const int t = threadIdx.x;
  const int b = blockIdx.x;

  unsigned int wreg[96];                          // rows +0,+1,+2 x 32 pairs
  #pragma unroll
  for (int j = 0; j < 96; ++j) wreg[j] = Wq[j*1024 + t];
  #pragma unroll
  for (int j = 0; j < 96; ++j) asm volatile("" : "+v"(wreg[j]));  // load-once pin

  #pragma unroll
  for (int c = 0; c < 8; ++c) {                   // row +3: pairs 4c..4c+3
    uint4 v;
    v.x = Wq[(96 + 4*c + 0)*1024 + t];
    v.y = Wq[(96 + 4*c + 1)*1024 + t];
    v.z = Wq[(96 + 4*c + 2)*1024 + t];
    v.w = Wq[(96 + 4*c + 3)*1024 + t];
    wlds[c*1024 + t] = v;
  }
  if (t < 144) h2[t] = 0u;
  float c_state = 0.f;
  const _Float16* xb = XP + (size_t)b*SEQ*G4 + t;
  float xcur = (float)xb[0];
  float* outb = out + (size_t)b*SEQ*H;
  const unsigned int* hq_base = h2 + (t & 3)*36;  // this thread's h quarter
  __syncthreads();

  #pragma unroll 1
  for (int s = 0; s < SEQ; ++s) {
    const int sn = (s + 1 < SEQ) ? (s + 1) : s;
    const _Float16 xnext = xb[(size_t)sn * G4];   // prefetch, used next iter

    float a0 = 0.f, a1 = 0.f, a2 = 0.f, a3 = 0.f; // quarter partials, rows +0..+3
    #pragma unroll
    for (int c = 0; c < 8; ++c) {
      const uint4 hq = *(const uint4*)(hq_base + 4*c);  // 4-addr multicast read
      a0 = FDOT2(wreg[ 0 + 4*c + 0], hq.x, a0);
      a0 = FDOT2(wreg[ 0 + 4*c + 1], hq.y, a0);
      a0 = FDOT2(wreg[ 0 + 4*c + 2], hq.z, a0);
      a0 = FDOT2(wreg[ 0 + 4*c + 3], hq.w, a0);
      a1 = FDOT2(wreg[32 + 4*c + 0], hq.x, a1);
      a1 = FDOT2(wreg[32 + 4*c + 1], hq.y, a1);
      a1 = FDOT2(wreg[32 + 4*c + 2], hq.z, a1);
      a1 = FDOT2(wreg[32 + 4*c + 3], hq.w, a1);
      a2 = FDOT2(wreg[64 + 4*c + 0], hq.x, a2);
      a2 = FDOT2(wreg[64 + 4*c + 1], hq.y, a2);
      a2 = FDOT2(wreg[64 + 4*c + 2], hq.z, a2);
      a2 = FDOT2(wreg[64 + 4*c + 3], hq.w, a2);
      const uint4 wv = wlds[c*1024 + t];
      a3 = FDOT2(wv.x, hq.x, a3);
      a3 = FDOT2(wv.y, hq.y, a3);
      a3 = FDOT2(wv.z, hq.z, a3);
      a3 = FDOT2(wv.w, hq.w, a3);
    }
    // quad butterfly: full dot for each of the 4 rows in all 4 quad lanes
    float s0 = a0 + dpp_xor1(a0); s0 += dpp_xor2(s0);
    float s1 = a1 + dpp_xor1(a1); s1 += dpp_xor2(s1);
    float s2 = a2 + dpp_xor1(a2); s2 += dpp_xor2(s2);
    float s3 = a3 + dpp_xor1(a3); s3 += dpp_xor2(s3);
    // thread t activates row t = 4*(t>>2) + (t&3): select own row
    const int c4 = t & 3;
    const float glo  = (c4 & 1) ? s1 : s0;
    const float ghi  = (c4 & 1) ? s3 : s2;
    const float gate = ((c4 & 2) ? ghi : glo) + xcur;

    // rows 0-255=i(sig), 256-511=f(sig), 512-767=g(tanh), 768-1023=o(sig);
    // branch is wave-uniform.
    float a;
    if (t < 512 || t >= 768) a = 1.f / (1.f + __expf(-gate));
    else                     a = 2.f / (1.f + __expf(-2.f*gate)) - 1.f;
    act[t] = a;
    __syncthreads();
    if (t < H) {
      const float gi = act[t], gf = act[H+t], gg = act[2*H+t], go = act[3*H+t];
      c_state = gf*c_state + gi*gg;
      const float th = 2.f / (1.f + __expf(-2.f*c_state)) - 1.f;
      const float h = go*th;
      outb[(size_t)s*H + t] = h;
      // element t -> f16 slot (t>>6)*72 + (t&63)   (padded quarter layout)
      ((_Float16*)h2)[(t >> 6)*72 + (t & 63)] = (_Float16)h;
      if (s == SEQ-1) {
        out[(size_t)BATCH*SEQ*H + (size_t)b*H + t] = h;                      // final h
        out[(size_t)BATCH*SEQ*H + (size_t)BATCH*H + (size_t)b*H + t] = c_state; // final c
      }
    }
    xcur = (float)xnext;
    __syncthreads();
  }
}

// ---------------------------------------------------------------------------
// ws layout: [ XP f16 256MB | Wihf f16 512KB | Wq u32 512KB | bias f32 4KB ]
// ---------------------------------------------------------------------------
extern "C" void kernel_launch(void* const* d_in, const int* in_sizes, int n_in,
                              void* d_out, int out_size, void* d_ws, size_t ws_size,
                              hipStream_t stream) {
  const float* x   = (const float*)d_in[0];
  const float* Wih = (const float*)d_in[1];
  const float* Whh = (const float*)d_in[2];
  const float* bih = (const float*)d_in[3];
  const float* bhh = (const float*)d_in[4];
  float* out = (float*)d_out;

  char* ws = (char*)d_ws;
  const size_t XP_BYTES = (size_t)M_TOT * G4 * sizeof(_Float16);   // 268435456
  _Float16*     XPp  = (_Float16*)ws;
  _Float16*     Wihf = (_Float16*)(ws + XP_BYTES);
  unsigned int* Wq   = (unsigned int*)(ws + XP_BYTES + 524288);
  float*        bias = (float*)(ws + XP_BYTES + 1048576);

  prep_kernel<<<dim3(1024),            dim3(256),  0, stream>>>(Wih, Whh, bih, bhh, Wihf, Wq, bias);
  xproj_gemm <<<dim3(M_TOT/BM, G4/BN), dim3(256),  0, stream>>>(x, Wihf, bias, XPp);
  lstm_scan  <<<dim3(BATCH),           dim3(1024), 0, stream>>>(XPp, Wq, out);
}